// Round 3
// baseline (534.405 us; speedup 1.0000x reference)
//
#include <hip/hip_runtime.h>

typedef __attribute__((ext_vector_type(8))) short short8;
typedef __attribute__((ext_vector_type(4))) float f32x4;
typedef unsigned short u16;

#define BB 4
#define TT 4096
#define CC 1024
#define HH 64

static __device__ __forceinline__ u16 f2bf(float f) {
    unsigned int u = __float_as_uint(f);
    unsigned int r = (u + 0x7FFFu + ((u >> 16) & 1u)) >> 16;  // RNE
    return (u16)r;
}

// attn LDS tile addressing: 64-u16 rows, 8 chunks of 8 u16; chunk XOR-swizzled by row&7.
static __device__ __forceinline__ int swz(int row, int chunk) {
    return row * 64 + ((chunk ^ (row & 7)) << 3);
}

static __device__ __forceinline__ int probe_isbf(const u16* xu, int tid) {
    // first wave probes x dtype; result broadcast via shared by caller
    int lane = tid & 63;
    int cnt = 0;
    for (int i = lane; i < 1024; i += 64) {
        u16 u = xu[2 * i];
        int e = (u >> 7) & 0xFF;
        cnt += (e >= 100 && e <= 140) ? 1 : 0;
    }
    for (int d = 1; d < 64; d <<= 1) cnt += __shfl_xor(cnt, d);
    return (cnt > 512) ? 1 : 0;
}

// ---------------- prep: dtype probe + W -> Wtp packed B-fragment order + zero counters.
// Blocks 0..191: W transpose (self-probing dtype). Block 192: zero cnt, publish flag.
// Wtp 16B-chunk index: (((proj*4+nt)*16 + kb)*2 + k2)*64 + quad*16 + l15
// holding W[k = kb*64+k2*32+quad*8 .. +8][n = proj*64+nt*16+l15].
__global__ void prep(const void* __restrict__ Wk, const void* __restrict__ Wq,
                     const void* __restrict__ Wv, const u16* __restrict__ xu,
                     u16* __restrict__ Wtp, int* __restrict__ flag, int* __restrict__ cnt) {
    __shared__ int sflag;
    if (threadIdx.x < 64) {
        int f = probe_isbf(xu, threadIdx.x);
        if (threadIdx.x == 0) sflag = f;
    }
    __syncthreads();
    const int isbf = sflag;

    if (blockIdx.x >= 192) {
        if (threadIdx.x < 256) cnt[threadIdx.x] = 0;
        if (threadIdx.x == 0) *flag = isbf;
        return;
    }

    int r = blockIdx.x;          // global output col 0..191
    int p = r >> 6;              // 0=q 1=k 2=v
    int n = r & 63;
    int nt = n >> 4, nl = n & 15;
    const void* W = (p == 0) ? Wq : (p == 1) ? Wk : Wv;
    int k0 = threadIdx.x * 4;    // 4 consecutive k per thread
    int kb = k0 >> 6, k2 = (k0 >> 5) & 1, quad = (k0 >> 3) & 3, half = (k0 >> 2) & 1;
    ushort4 v;
    if (isbf) {
        const u16* Wb = (const u16*)W;
        v.x = Wb[(k0 + 0) * HH + n]; v.y = Wb[(k0 + 1) * HH + n];
        v.z = Wb[(k0 + 2) * HH + n]; v.w = Wb[(k0 + 3) * HH + n];
    } else {
        const float* Wf = (const float*)W;
        v.x = f2bf(Wf[(k0 + 0) * HH + n]); v.y = f2bf(Wf[(k0 + 1) * HH + n]);
        v.z = f2bf(Wf[(k0 + 2) * HH + n]); v.w = f2bf(Wf[(k0 + 3) * HH + n]);
    }
    size_t off16 = ((size_t)((p * 4 + nt) * 16 + kb) * 2 + k2) * 64 + quad * 16 + nl;
    *reinterpret_cast<ushort4*>(Wtp + off16 * 8 + half * 4) = v;
}

// ---------------- QKV projection v5: 32 rows/block, fused LDS transpose, one barrier.
// 512 blocks x 256 thr (4 waves). Block = 32 rows of x staged into 64KB LDS; the
// k-loop is barrier-free: each B-fragment (from L2-resident Wtp) feeds TWO row-tile
// MFMAs (halves Wtp L2 traffic vs 16-row blocks). Wave w = col-tile w of q,k,v.
__global__ __launch_bounds__(256) void qkv_proj(const void* __restrict__ x,
                                                const u16* __restrict__ Wtp,
                                                u16* __restrict__ qo, u16* __restrict__ ko,
                                                u16* __restrict__ vo, const int* __restrict__ flag) {
    __shared__ __align__(16) u16 xs[32 * 1024];   // [row][k], 16B chunks swizzled by row&7
    __shared__ __align__(16) u16 tls[4][3][256];  // per-wave, per-proj 16x16 transpose tile
    const int isbf = *flag;
    const int tid = threadIdx.x;
    const int lane = tid & 63;
    const int w = tid >> 6;
    const int l15 = lane & 15;
    const int quad = lane >> 4;
    int phys = blockIdx.x;
    int rb = (phys & 7) * 64 + (phys >> 3);       // XCD-affine 32-row group, 0..511
    const int g0r = rb * 32;

    // ---- stage 32 rows of x (contiguous reads; swizzled 16B-chunk writes)
    #pragma unroll
    for (int j = 0; j < 16; j++) {
        int c = tid + j * 256;                    // 4096 chunks: row = c>>7, ck = c&127
        int row = c >> 7, ck = c & 127;
        int dst = row * 1024 + ((ck ^ (row & 7)) << 3);
        if (isbf) {
            uint4 d = *reinterpret_cast<const uint4*>((const u16*)x + (size_t)(g0r + row) * CC + ck * 8);
            *reinterpret_cast<uint4*>(xs + dst) = d;
        } else {
            const float4* pf = reinterpret_cast<const float4*>((const float*)x + (size_t)(g0r + row) * CC + ck * 8);
            float4 a0 = pf[0], a1 = pf[1];
            ushort4 lo; lo.x = f2bf(a0.x); lo.y = f2bf(a0.y); lo.z = f2bf(a0.z); lo.w = f2bf(a0.w);
            ushort4 hi; hi.x = f2bf(a1.x); hi.y = f2bf(a1.y); hi.z = f2bf(a1.z); hi.w = f2bf(a1.w);
            *reinterpret_cast<ushort4*>(xs + dst) = lo;
            *reinterpret_cast<ushort4*>(xs + dst + 4) = hi;
        }
    }
    __syncthreads();                              // the ONLY block-wide barrier

    f32x4 zero = {0.f, 0.f, 0.f, 0.f};
    f32x4 acc[3][2];                              // [proj][row-tile]
    #pragma unroll
    for (int i = 0; i < 3; i++) { acc[i][0] = zero; acc[i][1] = zero; }

    for (int kb = 0; kb < 16; kb++) {
        #pragma unroll
        for (int k2 = 0; k2 < 2; k2++) {
            int ck = kb * 8 + k2 * 4 + quad;
            // row-tile A-frags: rows l15 and 16+l15 (same swizzle since 16%8==0)
            int xo = ((ck ^ (l15 & 7)) << 3);
            short8 af0 = *reinterpret_cast<const short8*>(xs + l15 * 1024 + xo);
            short8 af1 = *reinterpret_cast<const short8*>(xs + (16 + l15) * 1024 + xo);
            #pragma unroll
            for (int p = 0; p < 3; p++) {
                short8 bf = *reinterpret_cast<const short8*>(
                    Wtp + ((((size_t)(p * 4 + w) * 16 + kb) * 2 + k2) * 64 + lane) * 8);
                acc[p][0] = __builtin_amdgcn_mfma_f32_16x16x32_bf16(af0, bf, acc[p][0], 0, 0, 0);
                acc[p][1] = __builtin_amdgcn_mfma_f32_16x16x32_bf16(af1, bf, acc[p][1], 0, 0, 0);
            }
        }
    }

    // ---- epilogue per row-tile: per-wave 16x16 LDS transpose, 8B coalesced stores
    const float qscale = 0.18033688011112042f;    // log2(e)/8
    #pragma unroll
    for (int rt = 0; rt < 2; rt++) {
        const int g0rt = g0r + rt * 16;
        #pragma unroll
        for (int p = 0; p < 3; p++) {
            if (p < 2) {
                float sc = (p == 0) ? qscale : 1.f;
                #pragma unroll
                for (int r = 0; r < 4; r++)       // [t(16)][c(16)]
                    tls[w][p][(quad * 4 + r) * 16 + l15] = f2bf(acc[p][rt][r] * sc);
            } else {
                #pragma unroll
                for (int r = 0; r < 4; r++)       // [c(16)][t(16)]
                    tls[w][p][l15 * 16 + quad * 4 + r] = f2bf(acc[p][rt][r]);
            }
        }
        // same-wave LDS RAW: compiler inserts lgkmcnt wait; no barrier needed
        #pragma unroll
        for (int p = 0; p < 2; p++) {             // q, k: row-major (g0rt+t)*64 + w*16+c
            int t = lane >> 2, seg = lane & 3;
            ushort4 d = *reinterpret_cast<const ushort4*>(&tls[w][p][t * 16 + seg * 4]);
            u16* dst = (p == 0) ? qo : ko;
            *reinterpret_cast<ushort4*>(dst + (size_t)(g0rt + t) * HH + w * 16 + seg * 4) = d;
        }
        {                                         // v: vo[b][kt][h][64keys]
            int c = lane >> 2, seg = lane & 3;
            ushort4 d = *reinterpret_cast<const ushort4*>(&tls[w][2][c * 16 + seg * 4]);
            int b = g0rt >> 12;
            int kt = (g0rt & 4095) >> 6;
            int toff = g0rt & 63;
            *reinterpret_cast<ushort4*>(vo + ((size_t)((b * 64 + kt) * 64 + w * 16 + c)) * 64 + toff + seg * 4) = d;
        }
    }
}

// ---------------- causal flash attention, 64 q-rows/block, split-K over 64-key tiles.
// vo is ktile-packed -> both K and V staging are contiguous 8KB reads.
// Pipeline: K/V for tile kt+nsplit prefetched into REGISTERS while tile kt computes.
// Split-K combine is FUSED: slot writes + threadfence + per-(b,qt) counter; the
// last-arriving split sums the L2-resident slots and writes the output (no finalize
// kernel). Splits dispatched high-qt first.
__global__ __launch_bounds__(256) void attn(const u16* __restrict__ qp, const u16* __restrict__ kp,
                                            const u16* __restrict__ vp, float* __restrict__ acco,
                                            float* __restrict__ accl, void* __restrict__ outv,
                                            const int* __restrict__ flag, int* __restrict__ cnt,
                                            int nsplit) {
    __shared__ __align__(16) u16 kst[64 * 64];   // (key, h), swizzled
    __shared__ __align__(16) u16 vts[64 * 64];   // (h, key), swizzled
    __shared__ __align__(16) u16 pb[4][16 * 64]; // per-wave P
    __shared__ int is_last;
    const int isbf = *flag;
    const int tid = threadIdx.x;
    const int lane = tid & 63;
    const int w = tid >> 6;           // 0..3
    const int l15 = lane & 15;
    const int quad = lane >> 4;

    int u = blockIdx.x;
    int b, qt, ks;
    if (nsplit == 1) {
        b = u >> 6;
        int raw = u & 63;
        qt = (raw & 1) ? (63 - (raw >> 1)) : (raw >> 1);
        ks = 0;
    } else {
        int per = 64 * nsplit;
        b = u / per;
        int rem = u - b * per;
        int i = rem / nsplit;
        qt = 63 - i;                  // descending qt: long blocks launch first
        ks = rem - i * nsplit;
    }
    int qbase = qt * 64;
    int diag = qt;
    int nkt = diag + 1;
    if (ks >= nkt) return;

    short8 aq[2];
    {
        const u16* qrow = qp + (size_t)(b * TT + qbase + w * 16 + l15) * HH;
        aq[0] = *reinterpret_cast<const short8*>(qrow + quad * 8);
        aq[1] = *reinterpret_cast<const short8*>(qrow + 32 + quad * 8);
    }

    // staging addresses (kt-invariant)
    const int cc0 = tid, cc1 = tid + 256;
    const int dst0 = swz(cc0 >> 3, cc0 & 7);
    const int dst1 = swz(cc1 >> 3, cc1 & 7);
    const u16* kbase = kp + (size_t)b * TT * HH;        // + kt*4096 + cc*8
    const u16* vbase = vp + (size_t)b * 64 * 64 * 64;   // + kt*4096 + cc*8

    f32x4 zero = {0.f, 0.f, 0.f, 0.f};
    f32x4 o[4];
    #pragma unroll
    for (int i = 0; i < 4; i++) o[i] = zero;
    f32x4 lsum = zero;

    // prologue prefetch: tile ks into registers
    uint4 rk0 = *reinterpret_cast<const uint4*>(kbase + (size_t)ks * 4096 + cc0 * 8);
    uint4 rk1 = *reinterpret_cast<const uint4*>(kbase + (size_t)ks * 4096 + cc1 * 8);
    uint4 rv0 = *reinterpret_cast<const uint4*>(vbase + (size_t)ks * 4096 + cc0 * 8);
    uint4 rv1 = *reinterpret_cast<const uint4*>(vbase + (size_t)ks * 4096 + cc1 * 8);

    for (int kt = ks; kt < nkt; kt += nsplit) {
        __syncthreads();              // previous iter's LDS reads done
        *reinterpret_cast<uint4*>(&kst[dst0]) = rk0;
        *reinterpret_cast<uint4*>(&kst[dst1]) = rk1;
        *reinterpret_cast<uint4*>(&vts[dst0]) = rv0;
        *reinterpret_cast<uint4*>(&vts[dst1]) = rv1;
        __syncthreads();              // staging visible
        // issue next tile's loads NOW; they fly under this tile's compute
        int ktn = kt + nsplit;
        if (ktn < nkt) {
            rk0 = *reinterpret_cast<const uint4*>(kbase + (size_t)ktn * 4096 + cc0 * 8);
            rk1 = *reinterpret_cast<const uint4*>(kbase + (size_t)ktn * 4096 + cc1 * 8);
            rv0 = *reinterpret_cast<const uint4*>(vbase + (size_t)ktn * 4096 + cc0 * 8);
            rv1 = *reinterpret_cast<const uint4*>(vbase + (size_t)ktn * 4096 + cc1 * 8);
        }
        // S = Q K^T (log2 domain via q pre-scale)
        f32x4 s[4];
        #pragma unroll
        for (int i = 0; i < 4; i++) s[i] = zero;
        __builtin_amdgcn_s_setprio(1);
        #pragma unroll
        for (int k2 = 0; k2 < 2; k2++) {
            #pragma unroll
            for (int nt = 0; nt < 4; nt++) {
                short8 bf = *reinterpret_cast<const short8*>(&kst[swz(nt * 16 + l15, k2 * 4 + quad)]);
                s[nt] = __builtin_amdgcn_mfma_f32_16x16x32_bf16(aq[k2], bf, s[nt], 0, 0, 0);
            }
        }
        __builtin_amdgcn_s_setprio(0);
        // p = exp2(s), causal mask on diagonal tile
        const int rg = qbase + w * 16 + quad * 4;
        const bool dm = (kt == diag);
        #pragma unroll
        for (int nt = 0; nt < 4; nt++) {
            int key = kt * 64 + nt * 16 + l15;
            #pragma unroll
            for (int r = 0; r < 4; r++) {
                float p = __builtin_amdgcn_exp2f(s[nt][r]);
                if (dm && key > rg + r) p = 0.f;
                s[nt][r] = p;
            }
        }
        #pragma unroll
        for (int nt = 0; nt < 4; nt++) lsum = lsum + s[nt];
        // P (C/D layout) -> per-wave LDS A-layout (same-wave RAW)
        #pragma unroll
        for (int nt = 0; nt < 4; nt++) {
            int chunk = nt * 2 + (l15 >> 3);
            int off = l15 & 7;
            #pragma unroll
            for (int r = 0; r < 4; r++) {
                int row = quad * 4 + r;
                pb[w][row * 64 + ((chunk ^ (row & 7)) << 3) + off] = f2bf(s[nt][r]);
            }
        }
        // O += P V
        __builtin_amdgcn_s_setprio(1);
        #pragma unroll
        for (int k2 = 0; k2 < 2; k2++) {
            short8 ap = *reinterpret_cast<const short8*>(&pb[w][swz(l15, k2 * 4 + quad)]);
            #pragma unroll
            for (int nt = 0; nt < 4; nt++) {
                short8 bv = *reinterpret_cast<const short8*>(&vts[swz(nt * 16 + l15, k2 * 4 + quad)]);
                o[nt] = __builtin_amdgcn_mfma_f32_16x16x32_bf16(ap, bv, o[nt], 0, 0, 0);
            }
        }
        __builtin_amdgcn_s_setprio(0);
    }

    #pragma unroll
    for (int d = 1; d < 16; d <<= 1) {
        f32x4 t;
        #pragma unroll
        for (int r = 0; r < 4; r++) t[r] = __shfl_xor(lsum[r], d);
        lsum = lsum + t;
    }
    const int g0 = b * TT + qbase + w * 16 + quad * 4;

    if (nsplit == 1) {
        f32x4 inv;
        #pragma unroll
        for (int r = 0; r < 4; r++) inv[r] = 1.0f / lsum[r];
        if (isbf) {
            u16* outp = (u16*)outv;
            #pragma unroll
            for (int nt = 0; nt < 4; nt++)
                #pragma unroll
                for (int r = 0; r < 4; r++)
                    outp[(size_t)(g0 + r) * HH + nt * 16 + l15] = f2bf(o[nt][r] * inv[r]);
        } else {
            float* outp = (float*)outv;
            #pragma unroll
            for (int nt = 0; nt < 4; nt++)
                #pragma unroll
                for (int r = 0; r < 4; r++)
                    outp[(size_t)(g0 + r) * HH + nt * 16 + l15] = o[nt][r] * inv[r];
        }
    } else {
        // slot-based partial writes: each (b,qt,ks) owns distinct rows of its slot
        float* accos = acco + (size_t)ks * (BB * TT * HH);
        float* accls = accl + (size_t)ks * (BB * TT);
        #pragma unroll
        for (int nt = 0; nt < 4; nt++)
            #pragma unroll
            for (int r = 0; r < 4; r++)
                accos[(size_t)(g0 + r) * HH + nt * 16 + l15] = o[nt][r];
        if (l15 == 0) {
            #pragma unroll
            for (int r = 0; r < 4; r++) accls[g0 + r] = lsum[r];
        }
        // decoupled completion: last split to finish combines all slots
        __threadfence();                           // release slot writes (device scope)
        const int nact = (nkt < nsplit) ? nkt : nsplit;
        if (tid == 0) {
            int old = atomicAdd(&cnt[b * 64 + qt], 1);
            is_last = (old == nact - 1) ? 1 : 0;
        }
        __syncthreads();
        if (is_last) {
            __threadfence();                       // acquire other splits' writes
            for (int i = tid; i < 64 * 16; i += 256) {   // 64 rows x 16 float4
                int row = i >> 4, c4 = i & 15;
                size_t rbase = (size_t)(b * TT + qbase + row);
                float4 ov = {0.f, 0.f, 0.f, 0.f};
                float l = 0.f;
                for (int s = 0; s < nact; s++) {
                    float4 t = reinterpret_cast<const float4*>(acco + (size_t)s * (BB * TT * HH) + rbase * HH)[c4];
                    ov.x += t.x; ov.y += t.y; ov.z += t.z; ov.w += t.w;
                    l += accl[(size_t)s * (BB * TT) + rbase];
                }
                float inv = 1.0f / l;
                if (isbf) {
                    ushort4 sv;
                    sv.x = f2bf(ov.x * inv); sv.y = f2bf(ov.y * inv);
                    sv.z = f2bf(ov.z * inv); sv.w = f2bf(ov.w * inv);
                    reinterpret_cast<ushort4*>((u16*)outv + rbase * HH)[c4] = sv;
                } else {
                    float4 sv = {ov.x * inv, ov.y * inv, ov.z * inv, ov.w * inv};
                    reinterpret_cast<float4*>((float*)outv + rbase * HH)[c4] = sv;
                }
            }
        }
    }
}

extern "C" void kernel_launch(void* const* d_in, const int* in_sizes, int n_in,
                              void* d_out, int out_size, void* d_ws, size_t ws_size,
                              hipStream_t stream) {
    const void* x  = d_in[0];
    const void* Wk = d_in[1];
    const void* Wq = d_in[2];
    const void* Wv = d_in[3];
    char* ws = (char*)d_ws;
    // ws: qo 0-2M | ko 2-4M | vo 4-6M | Wtp @6M(384K) | flag @6.75M | cnt @6.75M+4K (1K)
    //     acco @7M (nsplit slots x 4M) | accl @39M (nsplit slots x 64K)
    u16* qo = (u16*)(ws);
    u16* ko = (u16*)(ws + (size_t)2 * 1024 * 1024);
    u16* vo = (u16*)(ws + (size_t)4 * 1024 * 1024);
    u16* Wtp = (u16*)(ws + (size_t)6 * 1024 * 1024);
    int* flag = (int*)(ws + (size_t)6 * 1024 * 1024 + 768 * 1024);
    int* cnt  = (int*)(ws + (size_t)6 * 1024 * 1024 + 772 * 1024);
    float* acco = (float*)(ws + (size_t)7 * 1024 * 1024);
    float* accl = (float*)(ws + (size_t)39 * 1024 * 1024);

    const size_t need_split = (size_t)40 * 1024 * 1024;
    const int nsplit = (ws_size >= need_split) ? 8 : 1;

    prep<<<193, 256, 0, stream>>>(Wk, Wq, Wv, (const u16*)x, Wtp, flag, cnt);
    qkv_proj<<<512, 256, 0, stream>>>(x, Wtp, qo, ko, vo, flag);
    if (nsplit > 1) {
        attn<<<BB * 64 * nsplit, 256, 0, stream>>>(qo, ko, vo, acco, accl, d_out, flag, cnt, nsplit);
    } else {
        attn<<<BB * 64, 256, 0, stream>>>(qo, ko, vo, acco, accl, d_out, flag, cnt, 1);
    }
}

// Round 4
// 143.322 us; speedup vs baseline: 3.7287x; 3.7287x over previous
//
#include <hip/hip_runtime.h>

typedef __attribute__((ext_vector_type(8))) short short8;
typedef __attribute__((ext_vector_type(4))) float f32x4;
typedef unsigned short u16;

#define BB 4
#define TT 4096
#define CC 1024
#define HH 64

static __device__ __forceinline__ u16 f2bf(float f) {
    unsigned int u = __float_as_uint(f);
    unsigned int r = (u + 0x7FFFu + ((u >> 16) & 1u)) >> 16;  // RNE
    return (u16)r;
}

// attn LDS tile addressing: 64-u16 rows, 8 chunks of 8 u16; chunk XOR-swizzled by row&7.
static __device__ __forceinline__ int swz(int row, int chunk) {
    return row * 64 + ((chunk ^ (row & 7)) << 3);
}

static __device__ __forceinline__ int probe_isbf(const u16* xu, int tid) {
    int lane = tid & 63;
    int cnt = 0;
    for (int i = lane; i < 1024; i += 64) {
        u16 u = xu[2 * i];
        int e = (u >> 7) & 0xFF;
        cnt += (e >= 100 && e <= 140) ? 1 : 0;
    }
    for (int d = 1; d < 64; d <<= 1) cnt += __shfl_xor(cnt, d);
    return (cnt > 512) ? 1 : 0;
}

// ---------------- prep: dtype probe + W -> Wtp packed B-fragment order.
// Blocks 0..191: W transpose (self-probing dtype). Block 192: publish flag.
// Wtp 16B-chunk index: (((proj*4+nt)*16 + kb)*2 + k2)*64 + quad*16 + l15
// holding W[k = kb*64+k2*32+quad*8 .. +8][n = proj*64+nt*16+l15].
__global__ void prep(const void* __restrict__ Wk, const void* __restrict__ Wq,
                     const void* __restrict__ Wv, const u16* __restrict__ xu,
                     u16* __restrict__ Wtp, int* __restrict__ flag) {
    __shared__ int sflag;
    if (threadIdx.x < 64) {
        int f = probe_isbf(xu, threadIdx.x);
        if (threadIdx.x == 0) sflag = f;
    }
    __syncthreads();
    const int isbf = sflag;

    if (blockIdx.x >= 192) {
        if (threadIdx.x == 0) *flag = isbf;
        return;
    }

    int r = blockIdx.x;          // global output col 0..191
    int p = r >> 6;              // 0=q 1=k 2=v
    int n = r & 63;
    int nt = n >> 4, nl = n & 15;
    const void* W = (p == 0) ? Wq : (p == 1) ? Wk : Wv;
    int k0 = threadIdx.x * 4;    // 4 consecutive k per thread
    int kb = k0 >> 6, k2 = (k0 >> 5) & 1, quad = (k0 >> 3) & 3, half = (k0 >> 2) & 1;
    ushort4 v;
    if (isbf) {
        const u16* Wb = (const u16*)W;
        v.x = Wb[(k0 + 0) * HH + n]; v.y = Wb[(k0 + 1) * HH + n];
        v.z = Wb[(k0 + 2) * HH + n]; v.w = Wb[(k0 + 3) * HH + n];
    } else {
        const float* Wf = (const float*)W;
        v.x = f2bf(Wf[(k0 + 0) * HH + n]); v.y = f2bf(Wf[(k0 + 1) * HH + n]);
        v.z = f2bf(Wf[(k0 + 2) * HH + n]); v.w = f2bf(Wf[(k0 + 3) * HH + n]);
    }
    size_t off16 = ((size_t)((p * 4 + nt) * 16 + kb) * 2 + k2) * 64 + quad * 16 + nl;
    *reinterpret_cast<ushort4*>(Wtp + off16 * 8 + half * 4) = v;
}

// ---------------- QKV projection v5: 32 rows/block, fused LDS transpose, one barrier.
// 512 blocks x 256 thr (4 waves). Block = 32 rows of x staged into 64KB LDS; the
// k-loop is barrier-free: each B-fragment (from L2-resident Wtp) feeds TWO row-tile
// MFMAs (halves Wtp L2 traffic vs 16-row blocks). Wave w = col-tile w of q,k,v.
__global__ __launch_bounds__(256) void qkv_proj(const void* __restrict__ x,
                                                const u16* __restrict__ Wtp,
                                                u16* __restrict__ qo, u16* __restrict__ ko,
                                                u16* __restrict__ vo, const int* __restrict__ flag) {
    __shared__ __align__(16) u16 xs[32 * 1024];   // [row][k], 16B chunks swizzled by row&7
    __shared__ __align__(16) u16 tls[4][3][256];  // per-wave, per-proj 16x16 transpose tile
    const int isbf = *flag;
    const int tid = threadIdx.x;
    const int lane = tid & 63;
    const int w = tid >> 6;
    const int l15 = lane & 15;
    const int quad = lane >> 4;
    int phys = blockIdx.x;
    int rb = (phys & 7) * 64 + (phys >> 3);       // XCD-affine 32-row group, 0..511
    const int g0r = rb * 32;

    // ---- stage 32 rows of x (contiguous reads; swizzled 16B-chunk writes)
    #pragma unroll
    for (int j = 0; j < 16; j++) {
        int c = tid + j * 256;                    // 4096 chunks: row = c>>7, ck = c&127
        int row = c >> 7, ck = c & 127;
        int dst = row * 1024 + ((ck ^ (row & 7)) << 3);
        if (isbf) {
            uint4 d = *reinterpret_cast<const uint4*>((const u16*)x + (size_t)(g0r + row) * CC + ck * 8);
            *reinterpret_cast<uint4*>(xs + dst) = d;
        } else {
            const float4* pf = reinterpret_cast<const float4*>((const float*)x + (size_t)(g0r + row) * CC + ck * 8);
            float4 a0 = pf[0], a1 = pf[1];
            ushort4 lo; lo.x = f2bf(a0.x); lo.y = f2bf(a0.y); lo.z = f2bf(a0.z); lo.w = f2bf(a0.w);
            ushort4 hi; hi.x = f2bf(a1.x); hi.y = f2bf(a1.y); hi.z = f2bf(a1.z); hi.w = f2bf(a1.w);
            *reinterpret_cast<ushort4*>(xs + dst) = lo;
            *reinterpret_cast<ushort4*>(xs + dst + 4) = hi;
        }
    }
    __syncthreads();                              // the ONLY block-wide barrier

    f32x4 zero = {0.f, 0.f, 0.f, 0.f};
    f32x4 acc[3][2];                              // [proj][row-tile]
    #pragma unroll
    for (int i = 0; i < 3; i++) { acc[i][0] = zero; acc[i][1] = zero; }

    for (int kb = 0; kb < 16; kb++) {
        #pragma unroll
        for (int k2 = 0; k2 < 2; k2++) {
            int ck = kb * 8 + k2 * 4 + quad;
            // row-tile A-frags: rows l15 and 16+l15 (same swizzle since 16%8==0)
            int xo = ((ck ^ (l15 & 7)) << 3);
            short8 af0 = *reinterpret_cast<const short8*>(xs + l15 * 1024 + xo);
            short8 af1 = *reinterpret_cast<const short8*>(xs + (16 + l15) * 1024 + xo);
            #pragma unroll
            for (int p = 0; p < 3; p++) {
                short8 bf = *reinterpret_cast<const short8*>(
                    Wtp + ((((size_t)(p * 4 + w) * 16 + kb) * 2 + k2) * 64 + lane) * 8);
                acc[p][0] = __builtin_amdgcn_mfma_f32_16x16x32_bf16(af0, bf, acc[p][0], 0, 0, 0);
                acc[p][1] = __builtin_amdgcn_mfma_f32_16x16x32_bf16(af1, bf, acc[p][1], 0, 0, 0);
            }
        }
    }

    // ---- epilogue per row-tile: per-wave 16x16 LDS transpose, 8B coalesced stores
    const float qscale = 0.18033688011112042f;    // log2(e)/8
    #pragma unroll
    for (int rt = 0; rt < 2; rt++) {
        const int g0rt = g0r + rt * 16;
        #pragma unroll
        for (int p = 0; p < 3; p++) {
            if (p < 2) {
                float sc = (p == 0) ? qscale : 1.f;
                #pragma unroll
                for (int r = 0; r < 4; r++)       // [t(16)][c(16)]
                    tls[w][p][(quad * 4 + r) * 16 + l15] = f2bf(acc[p][rt][r] * sc);
            } else {
                #pragma unroll
                for (int r = 0; r < 4; r++)       // [c(16)][t(16)]
                    tls[w][p][l15 * 16 + quad * 4 + r] = f2bf(acc[p][rt][r]);
            }
        }
        // same-wave LDS RAW: compiler inserts lgkmcnt wait; no barrier needed
        #pragma unroll
        for (int p = 0; p < 2; p++) {             // q, k: row-major (g0rt+t)*64 + w*16+c
            int t = lane >> 2, seg = lane & 3;
            ushort4 d = *reinterpret_cast<const ushort4*>(&tls[w][p][t * 16 + seg * 4]);
            u16* dst = (p == 0) ? qo : ko;
            *reinterpret_cast<ushort4*>(dst + (size_t)(g0rt + t) * HH + w * 16 + seg * 4) = d;
        }
        {                                         // v: vo[b][kt][h][64keys]
            int c = lane >> 2, seg = lane & 3;
            ushort4 d = *reinterpret_cast<const ushort4*>(&tls[w][2][c * 16 + seg * 4]);
            int b = g0rt >> 12;
            int kt = (g0rt & 4095) >> 6;
            int toff = g0rt & 63;
            *reinterpret_cast<ushort4*>(vo + ((size_t)((b * 64 + kt) * 64 + w * 16 + c)) * 64 + toff + seg * 4) = d;
        }
    }
}

// ---------------- causal flash attention, 64 q-rows/block, split-K over 64-key tiles.
// vo is ktile-packed -> both K and V staging are contiguous 8KB reads.
// Pipeline: K/V for tile kt+nsplit prefetched into REGISTERS while tile kt computes.
// Split-K combine is SLOT-BASED (no atomics, no fences — the kernel boundary is the
// cross-XCD fence); splits dispatched high-qt first.
__global__ __launch_bounds__(256) void attn(const u16* __restrict__ qp, const u16* __restrict__ kp,
                                            const u16* __restrict__ vp, float* __restrict__ acco,
                                            float* __restrict__ accl, void* __restrict__ outv,
                                            const int* __restrict__ flag, int nsplit) {
    __shared__ __align__(16) u16 kst[64 * 64];   // (key, h), swizzled
    __shared__ __align__(16) u16 vts[64 * 64];   // (h, key), swizzled
    __shared__ __align__(16) u16 pb[4][16 * 64]; // per-wave P
    const int isbf = *flag;
    const int tid = threadIdx.x;
    const int lane = tid & 63;
    const int w = tid >> 6;           // 0..3
    const int l15 = lane & 15;
    const int quad = lane >> 4;

    int u = blockIdx.x;
    int b, qt, ks;
    if (nsplit == 1) {
        b = u >> 6;
        int raw = u & 63;
        qt = (raw & 1) ? (63 - (raw >> 1)) : (raw >> 1);
        ks = 0;
    } else {
        int per = 64 * nsplit;
        b = u / per;
        int rem = u - b * per;
        int i = rem / nsplit;
        qt = 63 - i;                  // descending qt: long blocks launch first
        ks = rem - i * nsplit;
    }
    int qbase = qt * 64;
    int diag = qt;
    int nkt = diag + 1;
    if (ks >= nkt) return;

    short8 aq[2];
    {
        const u16* qrow = qp + (size_t)(b * TT + qbase + w * 16 + l15) * HH;
        aq[0] = *reinterpret_cast<const short8*>(qrow + quad * 8);
        aq[1] = *reinterpret_cast<const short8*>(qrow + 32 + quad * 8);
    }

    // staging addresses (kt-invariant)
    const int cc0 = tid, cc1 = tid + 256;
    const int dst0 = swz(cc0 >> 3, cc0 & 7);
    const int dst1 = swz(cc1 >> 3, cc1 & 7);
    const u16* kbase = kp + (size_t)b * TT * HH;        // + kt*4096 + cc*8
    const u16* vbase = vp + (size_t)b * 64 * 64 * 64;   // + kt*4096 + cc*8

    f32x4 zero = {0.f, 0.f, 0.f, 0.f};
    f32x4 o[4];
    #pragma unroll
    for (int i = 0; i < 4; i++) o[i] = zero;
    f32x4 lsum = zero;

    // prologue prefetch: tile ks into registers
    uint4 rk0 = *reinterpret_cast<const uint4*>(kbase + (size_t)ks * 4096 + cc0 * 8);
    uint4 rk1 = *reinterpret_cast<const uint4*>(kbase + (size_t)ks * 4096 + cc1 * 8);
    uint4 rv0 = *reinterpret_cast<const uint4*>(vbase + (size_t)ks * 4096 + cc0 * 8);
    uint4 rv1 = *reinterpret_cast<const uint4*>(vbase + (size_t)ks * 4096 + cc1 * 8);

    for (int kt = ks; kt < nkt; kt += nsplit) {
        __syncthreads();              // previous iter's LDS reads done
        *reinterpret_cast<uint4*>(&kst[dst0]) = rk0;
        *reinterpret_cast<uint4*>(&kst[dst1]) = rk1;
        *reinterpret_cast<uint4*>(&vts[dst0]) = rv0;
        *reinterpret_cast<uint4*>(&vts[dst1]) = rv1;
        __syncthreads();              // staging visible
        // issue next tile's loads NOW; they fly under this tile's compute
        int ktn = kt + nsplit;
        if (ktn < nkt) {
            rk0 = *reinterpret_cast<const uint4*>(kbase + (size_t)ktn * 4096 + cc0 * 8);
            rk1 = *reinterpret_cast<const uint4*>(kbase + (size_t)ktn * 4096 + cc1 * 8);
            rv0 = *reinterpret_cast<const uint4*>(vbase + (size_t)ktn * 4096 + cc0 * 8);
            rv1 = *reinterpret_cast<const uint4*>(vbase + (size_t)ktn * 4096 + cc1 * 8);
        }
        // S = Q K^T (log2 domain via q pre-scale)
        f32x4 s[4];
        #pragma unroll
        for (int i = 0; i < 4; i++) s[i] = zero;
        __builtin_amdgcn_s_setprio(1);
        #pragma unroll
        for (int k2 = 0; k2 < 2; k2++) {
            #pragma unroll
            for (int nt = 0; nt < 4; nt++) {
                short8 bf = *reinterpret_cast<const short8*>(&kst[swz(nt * 16 + l15, k2 * 4 + quad)]);
                s[nt] = __builtin_amdgcn_mfma_f32_16x16x32_bf16(aq[k2], bf, s[nt], 0, 0, 0);
            }
        }
        __builtin_amdgcn_s_setprio(0);
        // p = exp2(s), causal mask on diagonal tile
        const int rg = qbase + w * 16 + quad * 4;
        const bool dm = (kt == diag);
        #pragma unroll
        for (int nt = 0; nt < 4; nt++) {
            int key = kt * 64 + nt * 16 + l15;
            #pragma unroll
            for (int r = 0; r < 4; r++) {
                float p = __builtin_amdgcn_exp2f(s[nt][r]);
                if (dm && key > rg + r) p = 0.f;
                s[nt][r] = p;
            }
        }
        #pragma unroll
        for (int nt = 0; nt < 4; nt++) lsum = lsum + s[nt];
        // P (C/D layout) -> per-wave LDS A-layout (same-wave RAW)
        #pragma unroll
        for (int nt = 0; nt < 4; nt++) {
            int chunk = nt * 2 + (l15 >> 3);
            int off = l15 & 7;
            #pragma unroll
            for (int r = 0; r < 4; r++) {
                int row = quad * 4 + r;
                pb[w][row * 64 + ((chunk ^ (row & 7)) << 3) + off] = f2bf(s[nt][r]);
            }
        }
        // O += P V
        __builtin_amdgcn_s_setprio(1);
        #pragma unroll
        for (int k2 = 0; k2 < 2; k2++) {
            short8 ap = *reinterpret_cast<const short8*>(&pb[w][swz(l15, k2 * 4 + quad)]);
            #pragma unroll
            for (int nt = 0; nt < 4; nt++) {
                short8 bv = *reinterpret_cast<const short8*>(&vts[swz(nt * 16 + l15, k2 * 4 + quad)]);
                o[nt] = __builtin_amdgcn_mfma_f32_16x16x32_bf16(ap, bv, o[nt], 0, 0, 0);
            }
        }
        __builtin_amdgcn_s_setprio(0);
    }

    #pragma unroll
    for (int d = 1; d < 16; d <<= 1) {
        f32x4 t;
        #pragma unroll
        for (int r = 0; r < 4; r++) t[r] = __shfl_xor(lsum[r], d);
        lsum = lsum + t;
    }
    const int g0 = b * TT + qbase + w * 16 + quad * 4;

    if (nsplit == 1) {
        f32x4 inv;
        #pragma unroll
        for (int r = 0; r < 4; r++) inv[r] = 1.0f / lsum[r];
        if (isbf) {
            u16* outp = (u16*)outv;
            #pragma unroll
            for (int nt = 0; nt < 4; nt++)
                #pragma unroll
                for (int r = 0; r < 4; r++)
                    outp[(size_t)(g0 + r) * HH + nt * 16 + l15] = f2bf(o[nt][r] * inv[r]);
        } else {
            float* outp = (float*)outv;
            #pragma unroll
            for (int nt = 0; nt < 4; nt++)
                #pragma unroll
                for (int r = 0; r < 4; r++)
                    outp[(size_t)(g0 + r) * HH + nt * 16 + l15] = o[nt][r] * inv[r];
        }
    } else {
        // slot-based partial writes: each (b,qt,ks) owns distinct rows of its slot
        float* accos = acco + (size_t)ks * (BB * TT * HH);
        float* accls = accl + (size_t)ks * (BB * TT);
        #pragma unroll
        for (int nt = 0; nt < 4; nt++)
            #pragma unroll
            for (int r = 0; r < 4; r++)
                accos[(size_t)(g0 + r) * HH + nt * 16 + l15] = o[nt][r];
        if (l15 == 0) {
            #pragma unroll
            for (int r = 0; r < 4; r++) accls[g0 + r] = lsum[r];
        }
    }
}

// ---------------- finalize: out = (sum over active slots of acco) / (sum accl)
__global__ __launch_bounds__(256) void attn_finalize(const float* __restrict__ acco,
                                                     const float* __restrict__ accl,
                                                     void* __restrict__ outv,
                                                     const int* __restrict__ flag, int nsplit) {
    const int isbf = *flag;
    int i = blockIdx.x * blockDim.x + threadIdx.x;   // float4 index over B*T*H
    int row = i >> 4;
    int qt = (row & (TT - 1)) >> 6;
    int nact = min(nsplit, qt + 1);
    float4 ov = reinterpret_cast<const float4*>(acco)[i];
    float l = accl[row];
    for (int s = 1; s < nact; s++) {
        float4 t = reinterpret_cast<const float4*>(acco + (size_t)s * (BB * TT * HH))[i];
        ov.x += t.x; ov.y += t.y; ov.z += t.z; ov.w += t.w;
        l += accl[(size_t)s * (BB * TT) + row];
    }
    float inv = 1.0f / l;
    if (isbf) {
        ushort4 s;
        s.x = f2bf(ov.x * inv); s.y = f2bf(ov.y * inv);
        s.z = f2bf(ov.z * inv); s.w = f2bf(ov.w * inv);
        reinterpret_cast<ushort4*>(outv)[i] = s;
    } else {
        float4 s = {ov.x * inv, ov.y * inv, ov.z * inv, ov.w * inv};
        reinterpret_cast<float4*>(outv)[i] = s;
    }
}

extern "C" void kernel_launch(void* const* d_in, const int* in_sizes, int n_in,
                              void* d_out, int out_size, void* d_ws, size_t ws_size,
                              hipStream_t stream) {
    const void* x  = d_in[0];
    const void* Wk = d_in[1];
    const void* Wq = d_in[2];
    const void* Wv = d_in[3];
    char* ws = (char*)d_ws;
    // ws: qo 0-2M | ko 2-4M | vo 4-6M | Wtp @6M(384K) | flag @6.75M
    //     acco @7M (nsplit slots x 4M) | accl @39M (nsplit slots x 64K)
    u16* qo = (u16*)(ws);
    u16* ko = (u16*)(ws + (size_t)2 * 1024 * 1024);
    u16* vo = (u16*)(ws + (size_t)4 * 1024 * 1024);
    u16* Wtp = (u16*)(ws + (size_t)6 * 1024 * 1024);
    int* flag = (int*)(ws + (size_t)6 * 1024 * 1024 + 768 * 1024);
    float* acco = (float*)(ws + (size_t)7 * 1024 * 1024);
    float* accl = (float*)(ws + (size_t)39 * 1024 * 1024);

    const size_t need_split = (size_t)40 * 1024 * 1024;
    const int nsplit = (ws_size >= need_split) ? 8 : 1;

    prep<<<193, 256, 0, stream>>>(Wk, Wq, Wv, (const u16*)x, Wtp, flag);
    qkv_proj<<<512, 256, 0, stream>>>(x, Wtp, qo, ko, vo, flag);
    if (nsplit > 1) {
        attn<<<BB * 64 * nsplit, 256, 0, stream>>>(qo, ko, vo, acco, accl, d_out, flag, nsplit);
        attn_finalize<<<(BB * TT * HH / 4) / 256, 256, 0, stream>>>(acco, accl, d_out, flag, nsplit);
    } else {
        attn<<<BB * 64, 256, 0, stream>>>(qo, ko, vo, acco, accl, d_out, flag, 1);
    }
}

// Round 5
// 142.379 us; speedup vs baseline: 3.7534x; 1.0066x over previous
//
#include <hip/hip_runtime.h>

typedef __attribute__((ext_vector_type(8))) short short8;
typedef __attribute__((ext_vector_type(4))) float f32x4;
typedef unsigned short u16;

#define BB 4
#define TT 4096
#define CC 1024
#define HH 64

static __device__ __forceinline__ u16 f2bf(float f) {
    unsigned int u = __float_as_uint(f);
    unsigned int r = (u + 0x7FFFu + ((u >> 16) & 1u)) >> 16;  // RNE
    return (u16)r;
}

// pack 2 f32 -> 2 bf16 in one u32 (lo = first arg); no builtin on gfx950 (T12)
static __device__ __forceinline__ unsigned int cvtpk(float lo, float hi) {
    unsigned int r;
    asm("v_cvt_pk_bf16_f32 %0, %1, %2" : "=v"(r) : "v"(lo), "v"(hi));
    return r;
}

// attn LDS tile addressing: 64-u16 rows, 8 chunks of 8 u16; chunk XOR-swizzled by row&7.
static __device__ __forceinline__ int swz(int row, int chunk) {
    return row * 64 + ((chunk ^ (row & 7)) << 3);
}

static __device__ __forceinline__ int probe_isbf(const u16* xu, int tid) {
    int lane = tid & 63;
    int cnt = 0;
    for (int i = lane; i < 1024; i += 64) {
        u16 u = xu[2 * i];
        int e = (u >> 7) & 0xFF;
        cnt += (e >= 100 && e <= 140) ? 1 : 0;
    }
    for (int d = 1; d < 64; d <<= 1) cnt += __shfl_xor(cnt, d);
    return (cnt > 512) ? 1 : 0;
}

// ---------------- prep: dtype probe + W -> Wtp packed B-fragment order.
// Blocks 0..191: W transpose (self-probing dtype). Block 192: publish flag.
__global__ void prep(const void* __restrict__ Wk, const void* __restrict__ Wq,
                     const void* __restrict__ Wv, const u16* __restrict__ xu,
                     u16* __restrict__ Wtp, int* __restrict__ flag) {
    __shared__ int sflag;
    if (threadIdx.x < 64) {
        int f = probe_isbf(xu, threadIdx.x);
        if (threadIdx.x == 0) sflag = f;
    }
    __syncthreads();
    const int isbf = sflag;

    if (blockIdx.x >= 192) {
        if (threadIdx.x == 0) *flag = isbf;
        return;
    }

    int r = blockIdx.x;          // global output col 0..191
    int p = r >> 6;              // 0=q 1=k 2=v
    int n = r & 63;
    int nt = n >> 4, nl = n & 15;
    const void* W = (p == 0) ? Wq : (p == 1) ? Wk : Wv;
    int k0 = threadIdx.x * 4;    // 4 consecutive k per thread
    int kb = k0 >> 6, k2 = (k0 >> 5) & 1, quad = (k0 >> 3) & 3, half = (k0 >> 2) & 1;
    ushort4 v;
    if (isbf) {
        const u16* Wb = (const u16*)W;
        v.x = Wb[(k0 + 0) * HH + n]; v.y = Wb[(k0 + 1) * HH + n];
        v.z = Wb[(k0 + 2) * HH + n]; v.w = Wb[(k0 + 3) * HH + n];
    } else {
        const float* Wf = (const float*)W;
        v.x = f2bf(Wf[(k0 + 0) * HH + n]); v.y = f2bf(Wf[(k0 + 1) * HH + n]);
        v.z = f2bf(Wf[(k0 + 2) * HH + n]); v.w = f2bf(Wf[(k0 + 3) * HH + n]);
    }
    size_t off16 = ((size_t)((p * 4 + nt) * 16 + kb) * 2 + k2) * 64 + quad * 16 + nl;
    *reinterpret_cast<ushort4*>(Wtp + off16 * 8 + half * 4) = v;
}

// ---------------- QKV projection v5: 32 rows/block, fused LDS transpose, one barrier.
__global__ __launch_bounds__(256) void qkv_proj(const void* __restrict__ x,
                                                const u16* __restrict__ Wtp,
                                                u16* __restrict__ qo, u16* __restrict__ ko,
                                                u16* __restrict__ vo, const int* __restrict__ flag) {
    __shared__ __align__(16) u16 xs[32 * 1024];   // [row][k], 16B chunks swizzled by row&7
    __shared__ __align__(16) u16 tls[4][3][256];  // per-wave, per-proj 16x16 transpose tile
    const int isbf = *flag;
    const int tid = threadIdx.x;
    const int lane = tid & 63;
    const int w = tid >> 6;
    const int l15 = lane & 15;
    const int quad = lane >> 4;
    int phys = blockIdx.x;
    int rb = (phys & 7) * 64 + (phys >> 3);       // XCD-affine 32-row group, 0..511
    const int g0r = rb * 32;

    // ---- stage 32 rows of x (contiguous reads; swizzled 16B-chunk writes)
    #pragma unroll
    for (int j = 0; j < 16; j++) {
        int c = tid + j * 256;                    // 4096 chunks: row = c>>7, ck = c&127
        int row = c >> 7, ck = c & 127;
        int dst = row * 1024 + ((ck ^ (row & 7)) << 3);
        if (isbf) {
            uint4 d = *reinterpret_cast<const uint4*>((const u16*)x + (size_t)(g0r + row) * CC + ck * 8);
            *reinterpret_cast<uint4*>(xs + dst) = d;
        } else {
            const float4* pf = reinterpret_cast<const float4*>((const float*)x + (size_t)(g0r + row) * CC + ck * 8);
            float4 a0 = pf[0], a1 = pf[1];
            ushort4 lo; lo.x = f2bf(a0.x); lo.y = f2bf(a0.y); lo.z = f2bf(a0.z); lo.w = f2bf(a0.w);
            ushort4 hi; hi.x = f2bf(a1.x); hi.y = f2bf(a1.y); hi.z = f2bf(a1.z); hi.w = f2bf(a1.w);
            *reinterpret_cast<ushort4*>(xs + dst) = lo;
            *reinterpret_cast<ushort4*>(xs + dst + 4) = hi;
        }
    }
    __syncthreads();                              // the ONLY block-wide barrier

    f32x4 zero = {0.f, 0.f, 0.f, 0.f};
    f32x4 acc[3][2];                              // [proj][row-tile]
    #pragma unroll
    for (int i = 0; i < 3; i++) { acc[i][0] = zero; acc[i][1] = zero; }

    for (int kb = 0; kb < 16; kb++) {
        #pragma unroll
        for (int k2 = 0; k2 < 2; k2++) {
            int ck = kb * 8 + k2 * 4 + quad;
            int xo = ((ck ^ (l15 & 7)) << 3);
            short8 af0 = *reinterpret_cast<const short8*>(xs + l15 * 1024 + xo);
            short8 af1 = *reinterpret_cast<const short8*>(xs + (16 + l15) * 1024 + xo);
            #pragma unroll
            for (int p = 0; p < 3; p++) {
                short8 bf = *reinterpret_cast<const short8*>(
                    Wtp + ((((size_t)(p * 4 + w) * 16 + kb) * 2 + k2) * 64 + lane) * 8);
                acc[p][0] = __builtin_amdgcn_mfma_f32_16x16x32_bf16(af0, bf, acc[p][0], 0, 0, 0);
                acc[p][1] = __builtin_amdgcn_mfma_f32_16x16x32_bf16(af1, bf, acc[p][1], 0, 0, 0);
            }
        }
    }

    // ---- epilogue per row-tile: per-wave 16x16 LDS transpose, 8B coalesced stores
    const float qscale = 0.18033688011112042f;    // log2(e)/8
    #pragma unroll
    for (int rt = 0; rt < 2; rt++) {
        const int g0rt = g0r + rt * 16;
        #pragma unroll
        for (int p = 0; p < 3; p++) {
            if (p < 2) {
                float sc = (p == 0) ? qscale : 1.f;
                #pragma unroll
                for (int r = 0; r < 4; r++)       // [t(16)][c(16)]
                    tls[w][p][(quad * 4 + r) * 16 + l15] = f2bf(acc[p][rt][r] * sc);
            } else {
                #pragma unroll
                for (int r = 0; r < 4; r++)       // [c(16)][t(16)]
                    tls[w][p][l15 * 16 + quad * 4 + r] = f2bf(acc[p][rt][r]);
            }
        }
        // same-wave LDS RAW: compiler inserts lgkmcnt wait; no barrier needed
        #pragma unroll
        for (int p = 0; p < 2; p++) {             // q, k: row-major (g0rt+t)*64 + w*16+c
            int t = lane >> 2, seg = lane & 3;
            ushort4 d = *reinterpret_cast<const ushort4*>(&tls[w][p][t * 16 + seg * 4]);
            u16* dst = (p == 0) ? qo : ko;
            *reinterpret_cast<ushort4*>(dst + (size_t)(g0rt + t) * HH + w * 16 + seg * 4) = d;
        }
        {                                         // v: vo[b][kt][h][64keys]
            int c = lane >> 2, seg = lane & 3;
            ushort4 d = *reinterpret_cast<const ushort4*>(&tls[w][2][c * 16 + seg * 4]);
            int b = g0rt >> 12;
            int kt = (g0rt & 4095) >> 6;
            int toff = g0rt & 63;
            *reinterpret_cast<ushort4*>(vo + ((size_t)((b * 64 + kt) * 64 + w * 16 + c)) * 64 + toff + seg * 4) = d;
        }
    }
}

// ---------------- causal flash attention, 64 q-rows/block, split-K over 64-key tiles.
// S computed TRANSPOSED: S^T = mfma(K_frag, Q_frag) (A/B frags have identical lane
// mapping, so this is a free operand swap). Thread (l15,quad) then holds P for 4
// CONTIGUOUS keys (quad*4+r) at q-col l15 -> P staging is 2 cvt_pk + 1 ds_write_b64
// per nt (vs 16 f2bf + 16 ds_write_b16), lsum is scalar, epilogue is float4 stores.
// K/V for tile kt+nsplit prefetched into registers while tile kt computes.
__global__ __launch_bounds__(256) void attn(const u16* __restrict__ qp, const u16* __restrict__ kp,
                                            const u16* __restrict__ vp, float* __restrict__ acco,
                                            float* __restrict__ accl, void* __restrict__ outv,
                                            const int* __restrict__ flag, int nsplit) {
    __shared__ __align__(16) u16 kst[64 * 64];   // (key, h), swizzled
    __shared__ __align__(16) u16 vts[64 * 64];   // (h, key), swizzled
    __shared__ __align__(16) u16 pb[4][16 * 64]; // per-wave P^T: [q(16)][key(64)], swizzled
    const int isbf = *flag;
    const int tid = threadIdx.x;
    const int lane = tid & 63;
    const int w = tid >> 6;           // 0..3
    const int l15 = lane & 15;
    const int quad = lane >> 4;

    int u = blockIdx.x;
    int b, qt, ks;
    if (nsplit == 1) {
        b = u >> 6;
        int raw = u & 63;
        qt = (raw & 1) ? (63 - (raw >> 1)) : (raw >> 1);
        ks = 0;
    } else {
        int per = 64 * nsplit;
        b = u / per;
        int rem = u - b * per;
        int i = rem / nsplit;
        qt = 63 - i;                  // descending qt: long blocks launch first
        ks = rem - i * nsplit;
    }
    int qbase = qt * 64;
    int diag = qt;
    int nkt = diag + 1;
    if (ks >= nkt) return;

    const int q_g = qbase + w * 16 + l15;     // this thread's q row (fixed)

    short8 aq[2];
    {
        const u16* qrow = qp + (size_t)(b * TT + q_g) * HH;
        aq[0] = *reinterpret_cast<const short8*>(qrow + quad * 8);
        aq[1] = *reinterpret_cast<const short8*>(qrow + 32 + quad * 8);
    }

    // staging addresses (kt-invariant)
    const int cc0 = tid, cc1 = tid + 256;
    const int dst0 = swz(cc0 >> 3, cc0 & 7);
    const int dst1 = swz(cc1 >> 3, cc1 & 7);
    const u16* kbase = kp + (size_t)b * TT * HH;        // + kt*4096 + cc*8
    const u16* vbase = vp + (size_t)b * 64 * 64 * 64;   // + kt*4096 + cc*8

    f32x4 zero = {0.f, 0.f, 0.f, 0.f};
    f32x4 o[4];                       // o[nt][r] = O^T[h=nt*16+quad*4+r][q=l15-col]
    #pragma unroll
    for (int i = 0; i < 4; i++) o[i] = zero;
    float lsum = 0.f;                 // partial denom for q = q_g (this thread's 16 keys/tile)

    // prologue prefetch: tile ks into registers
    uint4 rk0 = *reinterpret_cast<const uint4*>(kbase + (size_t)ks * 4096 + cc0 * 8);
    uint4 rk1 = *reinterpret_cast<const uint4*>(kbase + (size_t)ks * 4096 + cc1 * 8);
    uint4 rv0 = *reinterpret_cast<const uint4*>(vbase + (size_t)ks * 4096 + cc0 * 8);
    uint4 rv1 = *reinterpret_cast<const uint4*>(vbase + (size_t)ks * 4096 + cc1 * 8);

    for (int kt = ks; kt < nkt; kt += nsplit) {
        __syncthreads();              // previous iter's LDS reads done
        *reinterpret_cast<uint4*>(&kst[dst0]) = rk0;
        *reinterpret_cast<uint4*>(&kst[dst1]) = rk1;
        *reinterpret_cast<uint4*>(&vts[dst0]) = rv0;
        *reinterpret_cast<uint4*>(&vts[dst1]) = rv1;
        __syncthreads();              // staging visible
        // issue next tile's loads NOW; they fly under this tile's compute
        int ktn = kt + nsplit;
        if (ktn < nkt) {
            rk0 = *reinterpret_cast<const uint4*>(kbase + (size_t)ktn * 4096 + cc0 * 8);
            rk1 = *reinterpret_cast<const uint4*>(kbase + (size_t)ktn * 4096 + cc1 * 8);
            rv0 = *reinterpret_cast<const uint4*>(vbase + (size_t)ktn * 4096 + cc0 * 8);
            rv1 = *reinterpret_cast<const uint4*>(vbase + (size_t)ktn * 4096 + cc1 * 8);
        }
        // S^T = K Q^T (log2 domain via q pre-scale): s[nt][r] = S[q=l15][key=kt*64+nt*16+quad*4+r]
        f32x4 s[4];
        #pragma unroll
        for (int i = 0; i < 4; i++) s[i] = zero;
        __builtin_amdgcn_s_setprio(1);
        #pragma unroll
        for (int k2 = 0; k2 < 2; k2++) {
            #pragma unroll
            for (int nt = 0; nt < 4; nt++) {
                short8 af = *reinterpret_cast<const short8*>(&kst[swz(nt * 16 + l15, k2 * 4 + quad)]);
                s[nt] = __builtin_amdgcn_mfma_f32_16x16x32_bf16(af, aq[k2], s[nt], 0, 0, 0);
            }
        }
        __builtin_amdgcn_s_setprio(0);
        // p = exp2(s), causal mask on diagonal tile (key > q)
        const bool dm = (kt == diag);
        #pragma unroll
        for (int nt = 0; nt < 4; nt++) {
            int key0 = kt * 64 + nt * 16 + quad * 4;
            #pragma unroll
            for (int r = 0; r < 4; r++) {
                float p = __builtin_amdgcn_exp2f(s[nt][r]);
                if (dm && key0 + r > q_g) p = 0.f;
                s[nt][r] = p;
            }
        }
        #pragma unroll
        for (int nt = 0; nt < 4; nt++)
            lsum += (s[nt][0] + s[nt][1]) + (s[nt][2] + s[nt][3]);
        // P^T (4 contiguous keys/thread) -> per-wave LDS B-layout: 2 cvt_pk + 1 b64 store per nt
        #pragma unroll
        for (int nt = 0; nt < 4; nt++) {
            uint2 pk;
            pk.x = cvtpk(s[nt][0], s[nt][1]);
            pk.y = cvtpk(s[nt][2], s[nt][3]);
            int addr = swz(l15, nt * 2 + (quad >> 1)) + (quad & 1) * 4;  // u16 units
            *reinterpret_cast<uint2*>(&pb[w][addr]) = pk;
        }
        // O^T += V^T P^T (same-wave LDS RAW: compiler inserts lgkmcnt wait)
        __builtin_amdgcn_s_setprio(1);
        #pragma unroll
        for (int k2 = 0; k2 < 2; k2++) {
            short8 bp = *reinterpret_cast<const short8*>(&pb[w][swz(l15, k2 * 4 + quad)]);
            #pragma unroll
            for (int nt = 0; nt < 4; nt++) {
                short8 av = *reinterpret_cast<const short8*>(&vts[swz(nt * 16 + l15, k2 * 4 + quad)]);
                o[nt] = __builtin_amdgcn_mfma_f32_16x16x32_bf16(av, bp, o[nt], 0, 0, 0);
            }
        }
        __builtin_amdgcn_s_setprio(0);
    }

    // denom: sum the 4 quads' partials for q = q_g
    lsum += __shfl_xor(lsum, 16);
    lsum += __shfl_xor(lsum, 32);

    const size_t g0q = (size_t)(b * TT) + q_g;

    if (nsplit == 1) {
        float inv = 1.0f / lsum;
        if (isbf) {
            u16* outp = (u16*)outv;
            #pragma unroll
            for (int nt = 0; nt < 4; nt++) {
                ushort4 sv;
                sv.x = f2bf(o[nt][0] * inv); sv.y = f2bf(o[nt][1] * inv);
                sv.z = f2bf(o[nt][2] * inv); sv.w = f2bf(o[nt][3] * inv);
                *reinterpret_cast<ushort4*>(outp + g0q * HH + nt * 16 + quad * 4) = sv;
            }
        } else {
            float* outp = (float*)outv;
            #pragma unroll
            for (int nt = 0; nt < 4; nt++) {
                float4 sv = {o[nt][0] * inv, o[nt][1] * inv, o[nt][2] * inv, o[nt][3] * inv};
                *reinterpret_cast<float4*>(outp + g0q * HH + nt * 16 + quad * 4) = sv;
            }
        }
    } else {
        // slot-based partial writes: each (b,qt,ks) owns distinct rows of its slot
        float* accos = acco + (size_t)ks * (BB * TT * HH);
        float* accls = accl + (size_t)ks * (BB * TT);
        #pragma unroll
        for (int nt = 0; nt < 4; nt++) {
            float4 sv = {o[nt][0], o[nt][1], o[nt][2], o[nt][3]};
            *reinterpret_cast<float4*>(accos + g0q * HH + nt * 16 + quad * 4) = sv;
        }
        if (quad == 0) accls[g0q] = lsum;
    }
}

// ---------------- finalize: out = (sum over active slots of acco) / (sum accl)
__global__ __launch_bounds__(256) void attn_finalize(const float* __restrict__ acco,
                                                     const float* __restrict__ accl,
                                                     void* __restrict__ outv,
                                                     const int* __restrict__ flag, int nsplit) {
    const int isbf = *flag;
    int i = blockIdx.x * blockDim.x + threadIdx.x;   // float4 index over B*T*H
    int row = i >> 4;
    int qt = (row & (TT - 1)) >> 6;
    int nact = min(nsplit, qt + 1);
    float4 ov = reinterpret_cast<const float4*>(acco)[i];
    float l = accl[row];
    for (int s = 1; s < nact; s++) {
        float4 t = reinterpret_cast<const float4*>(acco + (size_t)s * (BB * TT * HH))[i];
        ov.x += t.x; ov.y += t.y; ov.z += t.z; ov.w += t.w;
        l += accl[(size_t)s * (BB * TT) + row];
    }
    float inv = 1.0f / l;
    if (isbf) {
        ushort4 s;
        s.x = f2bf(ov.x * inv); s.y = f2bf(ov.y * inv);
        s.z = f2bf(ov.z * inv); s.w = f2bf(ov.w * inv);
        reinterpret_cast<ushort4*>(outv)[i] = s;
    } else {
        float4 s = {ov.x * inv, ov.y * inv, ov.z * inv, ov.w * inv};
        reinterpret_cast<float4*>(outv)[i] = s;
    }
}

extern "C" void kernel_launch(void* const* d_in, const int* in_sizes, int n_in,
                              void* d_out, int out_size, void* d_ws, size_t ws_size,
                              hipStream_t stream) {
    const void* x  = d_in[0];
    const void* Wk = d_in[1];
    const void* Wq = d_in[2];
    const void* Wv = d_in[3];
    char* ws = (char*)d_ws;
    // ws: qo 0-2M | ko 2-4M | vo 4-6M | Wtp @6M(384K) | flag @6.75M
    //     acco @7M (nsplit slots x 4M) | accl @39M (nsplit slots x 64K)
    u16* qo = (u16*)(ws);
    u16* ko = (u16*)(ws + (size_t)2 * 1024 * 1024);
    u16* vo = (u16*)(ws + (size_t)4 * 1024 * 1024);
    u16* Wtp = (u16*)(ws + (size_t)6 * 1024 * 1024);
    int* flag = (int*)(ws + (size_t)6 * 1024 * 1024 + 768 * 1024);
    float* acco = (float*)(ws + (size_t)7 * 1024 * 1024);
    float* accl = (float*)(ws + (size_t)39 * 1024 * 1024);

    const size_t need_split = (size_t)40 * 1024 * 1024;
    const int nsplit = (ws_size >= need_split) ? 8 : 1;

    prep<<<193, 256, 0, stream>>>(Wk, Wq, Wv, (const u16*)x, Wtp, flag);
    qkv_proj<<<512, 256, 0, stream>>>(x, Wtp, qo, ko, vo, flag);
    if (nsplit > 1) {
        attn<<<BB * 64 * nsplit, 256, 0, stream>>>(qo, ko, vo, acco, accl, d_out, flag, nsplit);
        attn_finalize<<<(BB * TT * HH / 4) / 256, 256, 0, stream>>>(acco, accl, d_out, flag, nsplit);
    } else {
        attn<<<BB * 64, 256, 0, stream>>>(qo, ko, vo, acco, accl, d_out, flag, 1);
    }
}

// Round 6
// 139.796 us; speedup vs baseline: 3.8228x; 1.0185x over previous
//
#include <hip/hip_runtime.h>

typedef __attribute__((ext_vector_type(8))) short short8;
typedef __attribute__((ext_vector_type(4))) float f32x4;
typedef unsigned short u16;

#define BB 4
#define TT 4096
#define CC 1024
#define HH 64

static __device__ __forceinline__ u16 f2bf(float f) {
    unsigned int u = __float_as_uint(f);
    unsigned int r = (u + 0x7FFFu + ((u >> 16) & 1u)) >> 16;  // RNE
    return (u16)r;
}

// pack 2 f32 -> 2 bf16 in one u32 (lo = first arg); no builtin on gfx950 (T12)
static __device__ __forceinline__ unsigned int cvtpk(float lo, float hi) {
    unsigned int r;
    asm("v_cvt_pk_bf16_f32 %0, %1, %2" : "=v"(r) : "v"(lo), "v"(hi));
    return r;
}

// attn LDS tile addressing: 64-u16 rows, 8 chunks of 8 u16; chunk XOR-swizzled by row&7.
static __device__ __forceinline__ int swz(int row, int chunk) {
    return row * 64 + ((chunk ^ (row & 7)) << 3);
}

static __device__ __forceinline__ int probe_isbf(const u16* xu, int tid) {
    int lane = tid & 63;
    int cnt = 0;
    for (int i = lane; i < 1024; i += 64) {
        u16 u = xu[2 * i];
        int e = (u >> 7) & 0xFF;
        cnt += (e >= 100 && e <= 140) ? 1 : 0;
    }
    for (int d = 1; d < 64; d <<= 1) cnt += __shfl_xor(cnt, d);
    return (cnt > 512) ? 1 : 0;
}

// ---------------- prep: dtype probe + W -> Wtp packed B-fragment order.
__global__ void prep(const void* __restrict__ Wk, const void* __restrict__ Wq,
                     const void* __restrict__ Wv, const u16* __restrict__ xu,
                     u16* __restrict__ Wtp, int* __restrict__ flag) {
    __shared__ int sflag;
    if (threadIdx.x < 64) {
        int f = probe_isbf(xu, threadIdx.x);
        if (threadIdx.x == 0) sflag = f;
    }
    __syncthreads();
    const int isbf = sflag;

    if (blockIdx.x >= 192) {
        if (threadIdx.x == 0) *flag = isbf;
        return;
    }

    int r = blockIdx.x;          // global output col 0..191
    int p = r >> 6;              // 0=q 1=k 2=v
    int n = r & 63;
    int nt = n >> 4, nl = n & 15;
    const void* W = (p == 0) ? Wq : (p == 1) ? Wk : Wv;
    int k0 = threadIdx.x * 4;    // 4 consecutive k per thread
    int kb = k0 >> 6, k2 = (k0 >> 5) & 1, quad = (k0 >> 3) & 3, half = (k0 >> 2) & 1;
    ushort4 v;
    if (isbf) {
        const u16* Wb = (const u16*)W;
        v.x = Wb[(k0 + 0) * HH + n]; v.y = Wb[(k0 + 1) * HH + n];
        v.z = Wb[(k0 + 2) * HH + n]; v.w = Wb[(k0 + 3) * HH + n];
    } else {
        const float* Wf = (const float*)W;
        v.x = f2bf(Wf[(k0 + 0) * HH + n]); v.y = f2bf(Wf[(k0 + 1) * HH + n]);
        v.z = f2bf(Wf[(k0 + 2) * HH + n]); v.w = f2bf(Wf[(k0 + 3) * HH + n]);
    }
    size_t off16 = ((size_t)((p * 4 + nt) * 16 + kb) * 2 + k2) * 64 + quad * 16 + nl;
    *reinterpret_cast<ushort4*>(Wtp + off16 * 8 + half * 4) = v;
}

// ---------------- QKV projection v5: 32 rows/block, fused LDS transpose, one barrier.
__global__ __launch_bounds__(256) void qkv_proj(const void* __restrict__ x,
                                                const u16* __restrict__ Wtp,
                                                u16* __restrict__ qo, u16* __restrict__ ko,
                                                u16* __restrict__ vo, const int* __restrict__ flag) {
    __shared__ __align__(16) u16 xs[32 * 1024];   // [row][k], 16B chunks swizzled by row&7
    __shared__ __align__(16) u16 tls[4][3][256];  // per-wave, per-proj 16x16 transpose tile
    const int isbf = *flag;
    const int tid = threadIdx.x;
    const int lane = tid & 63;
    const int w = tid >> 6;
    const int l15 = lane & 15;
    const int quad = lane >> 4;
    int phys = blockIdx.x;
    int rb = (phys & 7) * 64 + (phys >> 3);       // XCD-affine 32-row group, 0..511
    const int g0r = rb * 32;

    // ---- stage 32 rows of x (contiguous reads; swizzled 16B-chunk writes)
    #pragma unroll
    for (int j = 0; j < 16; j++) {
        int c = tid + j * 256;                    // 4096 chunks: row = c>>7, ck = c&127
        int row = c >> 7, ck = c & 127;
        int dst = row * 1024 + ((ck ^ (row & 7)) << 3);
        if (isbf) {
            uint4 d = *reinterpret_cast<const uint4*>((const u16*)x + (size_t)(g0r + row) * CC + ck * 8);
            *reinterpret_cast<uint4*>(xs + dst) = d;
        } else {
            const float4* pf = reinterpret_cast<const float4*>((const float*)x + (size_t)(g0r + row) * CC + ck * 8);
            float4 a0 = pf[0], a1 = pf[1];
            ushort4 lo; lo.x = f2bf(a0.x); lo.y = f2bf(a0.y); lo.z = f2bf(a0.z); lo.w = f2bf(a0.w);
            ushort4 hi; hi.x = f2bf(a1.x); hi.y = f2bf(a1.y); hi.z = f2bf(a1.z); hi.w = f2bf(a1.w);
            *reinterpret_cast<ushort4*>(xs + dst) = lo;
            *reinterpret_cast<ushort4*>(xs + dst + 4) = hi;
        }
    }
    __syncthreads();                              // the ONLY block-wide barrier

    f32x4 zero = {0.f, 0.f, 0.f, 0.f};
    f32x4 acc[3][2];                              // [proj][row-tile]
    #pragma unroll
    for (int i = 0; i < 3; i++) { acc[i][0] = zero; acc[i][1] = zero; }

    for (int kb = 0; kb < 16; kb++) {
        #pragma unroll
        for (int k2 = 0; k2 < 2; k2++) {
            int ck = kb * 8 + k2 * 4 + quad;
            int xo = ((ck ^ (l15 & 7)) << 3);
            short8 af0 = *reinterpret_cast<const short8*>(xs + l15 * 1024 + xo);
            short8 af1 = *reinterpret_cast<const short8*>(xs + (16 + l15) * 1024 + xo);
            #pragma unroll
            for (int p = 0; p < 3; p++) {
                short8 bf = *reinterpret_cast<const short8*>(
                    Wtp + ((((size_t)(p * 4 + w) * 16 + kb) * 2 + k2) * 64 + lane) * 8);
                acc[p][0] = __builtin_amdgcn_mfma_f32_16x16x32_bf16(af0, bf, acc[p][0], 0, 0, 0);
                acc[p][1] = __builtin_amdgcn_mfma_f32_16x16x32_bf16(af1, bf, acc[p][1], 0, 0, 0);
            }
        }
    }

    // ---- epilogue per row-tile: per-wave 16x16 LDS transpose, 8B coalesced stores
    const float qscale = 0.18033688011112042f;    // log2(e)/8
    #pragma unroll
    for (int rt = 0; rt < 2; rt++) {
        const int g0rt = g0r + rt * 16;
        #pragma unroll
        for (int p = 0; p < 3; p++) {
            if (p < 2) {
                float sc = (p == 0) ? qscale : 1.f;
                #pragma unroll
                for (int r = 0; r < 4; r++)       // [t(16)][c(16)]
                    tls[w][p][(quad * 4 + r) * 16 + l15] = f2bf(acc[p][rt][r] * sc);
            } else {
                #pragma unroll
                for (int r = 0; r < 4; r++)       // [c(16)][t(16)]
                    tls[w][p][l15 * 16 + quad * 4 + r] = f2bf(acc[p][rt][r]);
            }
        }
        // same-wave LDS RAW: compiler inserts lgkmcnt wait; no barrier needed
        #pragma unroll
        for (int p = 0; p < 2; p++) {             // q, k: row-major (g0rt+t)*64 + w*16+c
            int t = lane >> 2, seg = lane & 3;
            ushort4 d = *reinterpret_cast<const ushort4*>(&tls[w][p][t * 16 + seg * 4]);
            u16* dst = (p == 0) ? qo : ko;
            *reinterpret_cast<ushort4*>(dst + (size_t)(g0rt + t) * HH + w * 16 + seg * 4) = d;
        }
        {                                         // v: vo[b][kt][h][64keys]
            int c = lane >> 2, seg = lane & 3;
            ushort4 d = *reinterpret_cast<const ushort4*>(&tls[w][2][c * 16 + seg * 4]);
            int b = g0rt >> 12;
            int kt = (g0rt & 4095) >> 6;
            int toff = g0rt & 63;
            *reinterpret_cast<ushort4*>(vo + ((size_t)((b * 64 + kt) * 64 + w * 16 + c)) * 64 + toff + seg * 4) = d;
        }
    }
}

// ---------------- one q-tile's work for one staged K/V tile (S^T form, R5 inner loop)
static __device__ __forceinline__ void attn_step(const u16* __restrict__ kstc,
                                                 const u16* __restrict__ vtsc,
                                                 u16* __restrict__ pbw,
                                                 const short8* aq, f32x4* o, float& lsum,
                                                 int kt, int q_g, bool dm, int l15, int quad) {
    f32x4 zero = {0.f, 0.f, 0.f, 0.f};
    f32x4 s[4];
    #pragma unroll
    for (int i = 0; i < 4; i++) s[i] = zero;
    __builtin_amdgcn_s_setprio(1);
    #pragma unroll
    for (int k2 = 0; k2 < 2; k2++) {
        #pragma unroll
        for (int nt = 0; nt < 4; nt++) {
            short8 af = *reinterpret_cast<const short8*>(&kstc[swz(nt * 16 + l15, k2 * 4 + quad)]);
            s[nt] = __builtin_amdgcn_mfma_f32_16x16x32_bf16(af, aq[k2], s[nt], 0, 0, 0);
        }
    }
    __builtin_amdgcn_s_setprio(0);
    #pragma unroll
    for (int nt = 0; nt < 4; nt++) {
        int key0 = kt * 64 + nt * 16 + quad * 4;
        #pragma unroll
        for (int r = 0; r < 4; r++) {
            float pv = __builtin_amdgcn_exp2f(s[nt][r]);
            if (dm && key0 + r > q_g) pv = 0.f;
            s[nt][r] = pv;
        }
    }
    #pragma unroll
    for (int nt = 0; nt < 4; nt++)
        lsum += (s[nt][0] + s[nt][1]) + (s[nt][2] + s[nt][3]);
    #pragma unroll
    for (int nt = 0; nt < 4; nt++) {
        uint2 pk;
        pk.x = cvtpk(s[nt][0], s[nt][1]);
        pk.y = cvtpk(s[nt][2], s[nt][3]);
        int addr = swz(l15, nt * 2 + (quad >> 1)) + (quad & 1) * 4;  // u16 units
        *reinterpret_cast<uint2*>(&pbw[addr]) = pk;
    }
    // same-wave LDS RAW: compiler inserts lgkmcnt wait
    __builtin_amdgcn_s_setprio(1);
    #pragma unroll
    for (int k2 = 0; k2 < 2; k2++) {
        short8 bp = *reinterpret_cast<const short8*>(&pbw[swz(l15, k2 * 4 + quad)]);
        #pragma unroll
        for (int nt = 0; nt < 4; nt++) {
            short8 av = *reinterpret_cast<const short8*>(&vtsc[swz(nt * 16 + l15, k2 * 4 + quad)]);
            o[nt] = __builtin_amdgcn_mfma_f32_16x16x32_bf16(av, bp, o[nt], 0, 0, 0);
        }
    }
    __builtin_amdgcn_s_setprio(0);
}

// ---------------- causal flash attention, qt-PAIRED: block (b,p,ks) handles qt=63-p
// AND qt=p -> constant 65 combined tiles => perfectly balanced blocks, 512 total.
// Single-barrier double-buffered K/V staging: step j: barrier; ds_write buf[j+1&1]
// (from regs prefetched 2 steps ago); issue loads for t_{j+2}; compute buf[j&1].
// Split-K combine slot-based, nsplit=4 (no atomics/fences; kernel boundary = fence).
__global__ __launch_bounds__(256) void attn(const u16* __restrict__ qp, const u16* __restrict__ kp,
                                            const u16* __restrict__ vp, float* __restrict__ acco,
                                            float* __restrict__ accl, void* __restrict__ outv,
                                            const int* __restrict__ flag, int nsplit) {
    __shared__ __align__(16) u16 kst[2][64 * 64];   // (key, h), swizzled, dbuf
    __shared__ __align__(16) u16 vts[2][64 * 64];   // (h, key), swizzled, dbuf
    __shared__ __align__(16) u16 pba[4][16 * 64];   // per-wave P^T for qtA
    __shared__ __align__(16) u16 pbb[4][16 * 64];   // per-wave P^T for qtB
    const int isbf = *flag;
    const int tid = threadIdx.x;
    const int lane = tid & 63;
    const int w = tid >> 6;           // 0..3
    const int l15 = lane & 15;
    const int quad = lane >> 4;

    int u = blockIdx.x;
    int per = 32 * nsplit;
    int b = u / per;
    int rem = u - b * per;
    int p = rem / nsplit;             // pair index 0..31
    int ks = rem - p * nsplit;
    const int qtA = 63 - p;           // large q-tile (>=32)
    const int qtB = p;                // small q-tile (<=31)

    const int q_gA = qtA * 64 + w * 16 + l15;
    const int q_gB = qtB * 64 + w * 16 + l15;

    short8 aqA[2], aqB[2];
    {
        const u16* qr = qp + (size_t)(b * TT + q_gA) * HH;
        aqA[0] = *reinterpret_cast<const short8*>(qr + quad * 8);
        aqA[1] = *reinterpret_cast<const short8*>(qr + 32 + quad * 8);
    }
    {
        const u16* qr = qp + (size_t)(b * TT + q_gB) * HH;
        aqB[0] = *reinterpret_cast<const short8*>(qr + quad * 8);
        aqB[1] = *reinterpret_cast<const short8*>(qr + 32 + quad * 8);
    }

    // staging addresses (tile-invariant)
    const int cc0 = tid, cc1 = tid + 256;
    const int dst0 = swz(cc0 >> 3, cc0 & 7);
    const int dst1 = swz(cc1 >> 3, cc1 & 7);
    const u16* kbase = kp + (size_t)b * TT * HH;        // + kt*4096 + cc*8
    const u16* vbase = vp + (size_t)b * 64 * 64 * 64;   // + kt*4096 + cc*8

    f32x4 zero = {0.f, 0.f, 0.f, 0.f};
    f32x4 oA[4], oB[4];
    #pragma unroll
    for (int i = 0; i < 4; i++) { oA[i] = zero; oB[i] = zero; }
    float lsumA = 0.f, lsumB = 0.f;

    const int nstep = (qtA - ks) / nsplit + 1;   // >= 8 (qtA>=32, ks<=3)

    // prologue: stage tile t0 into buf0; prefetch t1 into regs
    uint4 rk0, rk1, rv0, rv1;
    {
        size_t t0 = (size_t)ks * 4096;
        rk0 = *reinterpret_cast<const uint4*>(kbase + t0 + cc0 * 8);
        rk1 = *reinterpret_cast<const uint4*>(kbase + t0 + cc1 * 8);
        rv0 = *reinterpret_cast<const uint4*>(vbase + t0 + cc0 * 8);
        rv1 = *reinterpret_cast<const uint4*>(vbase + t0 + cc1 * 8);
    }
    *reinterpret_cast<uint4*>(&kst[0][dst0]) = rk0;
    *reinterpret_cast<uint4*>(&kst[0][dst1]) = rk1;
    *reinterpret_cast<uint4*>(&vts[0][dst0]) = rv0;
    *reinterpret_cast<uint4*>(&vts[0][dst1]) = rv1;
    if (nstep > 1) {
        size_t t1 = (size_t)(ks + nsplit) * 4096;
        rk0 = *reinterpret_cast<const uint4*>(kbase + t1 + cc0 * 8);
        rk1 = *reinterpret_cast<const uint4*>(kbase + t1 + cc1 * 8);
        rv0 = *reinterpret_cast<const uint4*>(vbase + t1 + cc0 * 8);
        rv1 = *reinterpret_cast<const uint4*>(vbase + t1 + cc1 * 8);
    }

    for (int j = 0; j < nstep; ++j) {
        __syncthreads();              // separates buf[cur] writes(j-1)/reads(j) AND buf[cur^1] reads(j-1)/writes(j)
        const int cur = j & 1;
        if (j + 1 < nstep) {          // write NEXT tile's buffer from regs
            *reinterpret_cast<uint4*>(&kst[cur ^ 1][dst0]) = rk0;
            *reinterpret_cast<uint4*>(&kst[cur ^ 1][dst1]) = rk1;
            *reinterpret_cast<uint4*>(&vts[cur ^ 1][dst0]) = rv0;
            *reinterpret_cast<uint4*>(&vts[cur ^ 1][dst1]) = rv1;
        }
        if (j + 2 < nstep) {          // issue loads for tile t_{j+2}; fly under compute
            size_t tn = (size_t)(ks + (j + 2) * nsplit) * 4096;
            rk0 = *reinterpret_cast<const uint4*>(kbase + tn + cc0 * 8);
            rk1 = *reinterpret_cast<const uint4*>(kbase + tn + cc1 * 8);
            rv0 = *reinterpret_cast<const uint4*>(vbase + tn + cc0 * 8);
            rv1 = *reinterpret_cast<const uint4*>(vbase + tn + cc1 * 8);
        }
        const int kt = ks + j * nsplit;
        attn_step(&kst[cur][0], &vts[cur][0], &pba[w][0], aqA, oA, lsumA,
                  kt, q_gA, kt == qtA, l15, quad);
        if (kt <= qtB)
            attn_step(&kst[cur][0], &vts[cur][0], &pbb[w][0], aqB, oB, lsumB,
                      kt, q_gB, kt == qtB, l15, quad);
    }

    // denom: sum the 4 quads' partials (q fixed per thread at l15)
    lsumA += __shfl_xor(lsumA, 16);
    lsumA += __shfl_xor(lsumA, 32);
    lsumB += __shfl_xor(lsumB, 16);
    lsumB += __shfl_xor(lsumB, 32);

    const size_t g0qA = (size_t)(b * TT) + q_gA;
    const size_t g0qB = (size_t)(b * TT) + q_gB;

    if (nsplit == 1) {
        float invA = 1.0f / lsumA;
        float invB = 1.0f / lsumB;
        if (isbf) {
            u16* outp = (u16*)outv;
            #pragma unroll
            for (int nt = 0; nt < 4; nt++) {
                ushort4 sa, sb;
                sa.x = f2bf(oA[nt][0] * invA); sa.y = f2bf(oA[nt][1] * invA);
                sa.z = f2bf(oA[nt][2] * invA); sa.w = f2bf(oA[nt][3] * invA);
                sb.x = f2bf(oB[nt][0] * invB); sb.y = f2bf(oB[nt][1] * invB);
                sb.z = f2bf(oB[nt][2] * invB); sb.w = f2bf(oB[nt][3] * invB);
                *reinterpret_cast<ushort4*>(outp + g0qA * HH + nt * 16 + quad * 4) = sa;
                *reinterpret_cast<ushort4*>(outp + g0qB * HH + nt * 16 + quad * 4) = sb;
            }
        } else {
            float* outp = (float*)outv;
            #pragma unroll
            for (int nt = 0; nt < 4; nt++) {
                float4 sa = {oA[nt][0] * invA, oA[nt][1] * invA, oA[nt][2] * invA, oA[nt][3] * invA};
                float4 sb = {oB[nt][0] * invB, oB[nt][1] * invB, oB[nt][2] * invB, oB[nt][3] * invB};
                *reinterpret_cast<float4*>(outp + g0qA * HH + nt * 16 + quad * 4) = sa;
                *reinterpret_cast<float4*>(outp + g0qB * HH + nt * 16 + quad * 4) = sb;
            }
        }
    } else {
        // slot-based partial writes: (b,qt,ks) owns distinct rows of slot ks
        float* accos = acco + (size_t)ks * (BB * TT * HH);
        float* accls = accl + (size_t)ks * (BB * TT);
        #pragma unroll
        for (int nt = 0; nt < 4; nt++) {
            float4 sv = {oA[nt][0], oA[nt][1], oA[nt][2], oA[nt][3]};
            *reinterpret_cast<float4*>(accos + g0qA * HH + nt * 16 + quad * 4) = sv;
        }
        if (quad == 0) accls[g0qA] = lsumA;
        if (ks <= qtB) {
            #pragma unroll
            for (int nt = 0; nt < 4; nt++) {
                float4 sv = {oB[nt][0], oB[nt][1], oB[nt][2], oB[nt][3]};
                *reinterpret_cast<float4*>(accos + g0qB * HH + nt * 16 + quad * 4) = sv;
            }
            if (quad == 0) accls[g0qB] = lsumB;
        }
    }
}

// ---------------- finalize: out = (sum over active slots of acco) / (sum accl)
__global__ __launch_bounds__(256) void attn_finalize(const float* __restrict__ acco,
                                                     const float* __restrict__ accl,
                                                     void* __restrict__ outv,
                                                     const int* __restrict__ flag, int nsplit) {
    const int isbf = *flag;
    int i = blockIdx.x * blockDim.x + threadIdx.x;   // float4 index over B*T*H
    int row = i >> 4;
    int qt = (row & (TT - 1)) >> 6;
    int nact = min(nsplit, qt + 1);
    float4 ov = reinterpret_cast<const float4*>(acco)[i];
    float l = accl[row];
    for (int s = 1; s < nact; s++) {
        float4 t = reinterpret_cast<const float4*>(acco + (size_t)s * (BB * TT * HH))[i];
        ov.x += t.x; ov.y += t.y; ov.z += t.z; ov.w += t.w;
        l += accl[(size_t)s * (BB * TT) + row];
    }
    float inv = 1.0f / l;
    if (isbf) {
        ushort4 s;
        s.x = f2bf(ov.x * inv); s.y = f2bf(ov.y * inv);
        s.z = f2bf(ov.z * inv); s.w = f2bf(ov.w * inv);
        reinterpret_cast<ushort4*>(outv)[i] = s;
    } else {
        float4 s = {ov.x * inv, ov.y * inv, ov.z * inv, ov.w * inv};
        reinterpret_cast<float4*>(outv)[i] = s;
    }
}

extern "C" void kernel_launch(void* const* d_in, const int* in_sizes, int n_in,
                              void* d_out, int out_size, void* d_ws, size_t ws_size,
                              hipStream_t stream) {
    const void* x  = d_in[0];
    const void* Wk = d_in[1];
    const void* Wq = d_in[2];
    const void* Wv = d_in[3];
    char* ws = (char*)d_ws;
    // ws: qo 0-2M | ko 2-4M | vo 4-6M | Wtp @6M(384K) | flag @6.75M
    //     acco @7M (4 slots x 4M) | accl @39M (4 slots x 64K)
    u16* qo = (u16*)(ws);
    u16* ko = (u16*)(ws + (size_t)2 * 1024 * 1024);
    u16* vo = (u16*)(ws + (size_t)4 * 1024 * 1024);
    u16* Wtp = (u16*)(ws + (size_t)6 * 1024 * 1024);
    int* flag = (int*)(ws + (size_t)6 * 1024 * 1024 + 768 * 1024);
    float* acco = (float*)(ws + (size_t)7 * 1024 * 1024);
    float* accl = (float*)(ws + (size_t)39 * 1024 * 1024);

    const size_t need_split = (size_t)40 * 1024 * 1024;
    const int nsplit = (ws_size >= need_split) ? 4 : 1;

    prep<<<193, 256, 0, stream>>>(Wk, Wq, Wv, (const u16*)x, Wtp, flag);
    qkv_proj<<<512, 256, 0, stream>>>(x, Wtp, qo, ko, vo, flag);
    attn<<<BB * 32 * nsplit, 256, 0, stream>>>(qo, ko, vo, acco, accl, d_out, flag, nsplit);
    if (nsplit > 1) {
        attn_finalize<<<(BB * TT * HH / 4) / 256, 256, 0, stream>>>(acco, accl, d_out, flag, nsplit);
    }
}